// Round 1
// baseline (640.976 us; speedup 1.0000x reference)
//
#include <hip/hip_runtime.h>

#define L_SEQ   768
#define N_MSA   256
#define SEQ_D   22
#define MSA_D   23
#define M_DIM   256
#define Z_DIM   128
#define NBITS   14
#define RELCLIP 32
#define ROWS    16

// ---------------------------------------------------------------------------
// Per-position tables:
//   add_m[l][c] = (seq[l] @ Ws)[c] + bs[c] + (bits(l) @ Wpos2)[c] + bpos2[c] + bmsa[c]
//   sq[l][c]    = (seq[l] @ Wq)[c] + bq[c]
//   sk[l][c]    = (seq[l] @ Wk)[c] + bk[c]
// ---------------------------------------------------------------------------
__global__ __launch_bounds__(256) void precompute_kernel(
    const float* __restrict__ seq, const float* __restrict__ Ws,
    const float* __restrict__ bs,  const float* __restrict__ bmsa,
    const float* __restrict__ Wq,  const float* __restrict__ bq,
    const float* __restrict__ Wk,  const float* __restrict__ bk,
    const float* __restrict__ Wpos2, const float* __restrict__ bpos2,
    float* __restrict__ add_m, float* __restrict__ sq_t, float* __restrict__ sk_t) {
  const int l   = blockIdx.x;
  const int tid = threadIdx.x;
  __shared__ float srow[SEQ_D];
  if (tid < SEQ_D) srow[tid] = seq[l * SEQ_D + tid];
  __syncthreads();

  // m_dim = 256 = blockDim
  float acc = bs[tid] + bpos2[tid] + bmsa[tid];
#pragma unroll
  for (int d = 0; d < SEQ_D; ++d) acc += srow[d] * Ws[d * M_DIM + tid];
#pragma unroll
  for (int k = 0; k < NBITS; ++k)
    if ((l >> k) & 1) acc += Wpos2[k * M_DIM + tid];
  add_m[l * M_DIM + tid] = acc;

  if (tid < Z_DIM) {
    float aq = bq[tid], ak = bk[tid];
#pragma unroll
    for (int d = 0; d < SEQ_D; ++d) {
      const float sv = srow[d];
      aq += sv * Wq[d * Z_DIM + tid];
      ak += sv * Wk[d * Z_DIM + tid];
    }
    sq_t[l * Z_DIM + tid] = aq;
    sk_t[l * Z_DIM + tid] = ak;
  }
}

// ---------------------------------------------------------------------------
// m[n][l][c] = msa[n][l][:] @ Wmsa[:, c]  + add_m[l][c]
// Block = 256 threads (one per c). ROWS consecutive (n,l) rows per block.
// msa row values are block-uniform -> uniform addresses -> scalar loads
// (s_load) feeding one-SGPR-operand v_fmac; Wmsa column lives in 23 VGPRs.
// ---------------------------------------------------------------------------
__global__ __launch_bounds__(256) void m_kernel(
    const float* __restrict__ msa, const float* __restrict__ Wmsa,
    const float* __restrict__ add_m, float* __restrict__ out_m) {
  const int tid = threadIdx.x;
  float w[MSA_D];
#pragma unroll
  for (int k = 0; k < MSA_D; ++k) w[k] = Wmsa[k * M_DIM + tid];

  const long r0 = (long)blockIdx.x * ROWS;   // flat row index n*L + l
  const int  l0 = (int)(r0 % L_SEQ);         // 768 % 16 == 0 -> no wrap inside block
  const float* __restrict__ mrow = msa + r0 * MSA_D;

#pragma unroll
  for (int r = 0; r < ROWS; ++r) {
    float acc = add_m[(l0 + r) * M_DIM + tid];
#pragma unroll
    for (int k = 0; k < MSA_D; ++k) acc += mrow[r * MSA_D + k] * w[k];
    out_m[(r0 + r) * M_DIM + tid] = acc;
  }
}

// ---------------------------------------------------------------------------
// z[i][j][c] = sq[j][c] + sk[i][c] + Wpos[clip(j-i,+-32)+32][c] + bpos[c]
// All float4. One (i, j-chunk of 96) per block; 8 j's per block-iteration.
// ---------------------------------------------------------------------------
__global__ __launch_bounds__(256) void z_kernel(
    const float* __restrict__ sq_t, const float* __restrict__ sk_t,
    const float* __restrict__ Wpos, const float* __restrict__ bpos,
    float* __restrict__ out_z) {
  const int i      = blockIdx.x >> 3;
  const int jchunk = blockIdx.x & 7;         // 8 chunks of 96 j's
  const int c4     = threadIdx.x & 31;       // float4 column slot (c = 4*c4)
  const int jlane  = threadIdx.x >> 5;       // 0..7

  const float4* __restrict__ sq4 = (const float4*)sq_t;
  const float4* __restrict__ wp4 = (const float4*)Wpos;

  float4 base = ((const float4*)sk_t)[i * (Z_DIM / 4) + c4];
  const float4 bp = ((const float4*)bpos)[c4];
  base.x += bp.x; base.y += bp.y; base.z += bp.z; base.w += bp.w;

  float4* __restrict__ out4 = (float4*)out_z + (long)i * (L_SEQ * (Z_DIM / 4));
  const int jend = jchunk * 96 + 96;
  for (int j = jchunk * 96 + jlane; j < jend; j += 8) {
    const float4 q = sq4[j * (Z_DIM / 4) + c4];
    int rel = j - i;
    rel = rel < -RELCLIP ? -RELCLIP : (rel > RELCLIP ? RELCLIP : rel);
    rel += RELCLIP;
    const float4 wv = wp4[rel * (Z_DIM / 4) + c4];
    float4 o;
    o.x = base.x + q.x + wv.x;
    o.y = base.y + q.y + wv.y;
    o.z = base.z + q.z + wv.z;
    o.w = base.w + q.w + wv.w;
    out4[(long)j * (Z_DIM / 4) + c4] = o;
  }
}

extern "C" void kernel_launch(void* const* d_in, const int* in_sizes, int n_in,
                              void* d_out, int out_size, void* d_ws, size_t ws_size,
                              hipStream_t stream) {
  const float* seq   = (const float*)d_in[0];
  const float* msa   = (const float*)d_in[1];
  const float* Wmsa  = (const float*)d_in[2];
  const float* bmsa  = (const float*)d_in[3];
  const float* Ws    = (const float*)d_in[4];
  const float* bs    = (const float*)d_in[5];
  const float* Wq    = (const float*)d_in[6];
  const float* bq    = (const float*)d_in[7];
  const float* Wk    = (const float*)d_in[8];
  const float* bk    = (const float*)d_in[9];
  const float* Wpos  = (const float*)d_in[10];
  const float* bpos  = (const float*)d_in[11];
  const float* Wpos2 = (const float*)d_in[12];
  const float* bpos2 = (const float*)d_in[13];

  float* out_m = (float*)d_out;
  float* out_z = out_m + (long)N_MSA * L_SEQ * M_DIM;

  float* add_m = (float*)d_ws;                 // [768][256]
  float* sq_t  = add_m + L_SEQ * M_DIM;        // [768][128]
  float* sk_t  = sq_t + L_SEQ * Z_DIM;         // [768][128]

  precompute_kernel<<<L_SEQ, 256, 0, stream>>>(seq, Ws, bs, bmsa, Wq, bq, Wk, bk,
                                               Wpos2, bpos2, add_m, sq_t, sk_t);
  m_kernel<<<(N_MSA * L_SEQ) / ROWS, 256, 0, stream>>>(msa, Wmsa, add_m, out_m);
  z_kernel<<<L_SEQ * 8, 256, 0, stream>>>(sq_t, sk_t, Wpos, bpos, out_z);
}

// Round 3
// 607.412 us; speedup vs baseline: 1.0553x; 1.0553x over previous
//
#include <hip/hip_runtime.h>

#define L_SEQ   768
#define N_MSA   256
#define SEQ_D   22
#define MSA_D   23
#define M_DIM   256
#define Z_DIM   128
#define NBITS   14
#define RELCLIP 32

#define M_ROWS_PER_BLOCK 32
#define MBLOCKS ((N_MSA * L_SEQ) / M_ROWS_PER_BLOCK)   // 6144
#define ZBLOCKS (L_SEQ * 8)                            // 6144 (8 j-chunks of 96)

// ---------------------------------------------------------------------------
// Per-position tables (tiny, ~5 us):
//   add_m[l][c] = (seq[l]@Ws)[c] + bs[c] + (bits(l)@Wpos2)[c] + bpos2[c] + bmsa[c]
//   sq_t[l][c]  = (seq[l]@Wq)[c] + bq[c]
//   skb_t[l][c] = (seq[l]@Wk)[c] + bk[c] + bpos[c]          (bpos folded in)
// ---------------------------------------------------------------------------
__global__ __launch_bounds__(256) void precompute_kernel(
    const float* __restrict__ seq, const float* __restrict__ Ws,
    const float* __restrict__ bs,  const float* __restrict__ bmsa,
    const float* __restrict__ Wq,  const float* __restrict__ bq,
    const float* __restrict__ Wk,  const float* __restrict__ bk,
    const float* __restrict__ bpos,
    const float* __restrict__ Wpos2, const float* __restrict__ bpos2,
    float* __restrict__ add_m, float* __restrict__ sq_t, float* __restrict__ skb_t) {
  const int l   = blockIdx.x;
  const int tid = threadIdx.x;
  __shared__ float srow[SEQ_D];
  if (tid < SEQ_D) srow[tid] = seq[l * SEQ_D + tid];
  __syncthreads();

  float acc = bs[tid] + bpos2[tid] + bmsa[tid];
#pragma unroll 2
  for (int d = 0; d < SEQ_D; ++d) acc = fmaf(srow[d], Ws[d * M_DIM + tid], acc);
#pragma unroll 2
  for (int k = 0; k < NBITS; ++k)
    if ((l >> k) & 1) acc += Wpos2[k * M_DIM + tid];
  add_m[l * M_DIM + tid] = acc;

  if (tid < Z_DIM) {
    float aq = bq[tid], ak = bk[tid] + bpos[tid];
#pragma unroll 2
    for (int d = 0; d < SEQ_D; ++d) {
      const float sv = srow[d];
      aq = fmaf(sv, Wq[d * Z_DIM + tid], aq);
      ak = fmaf(sv, Wk[d * Z_DIM + tid], ak);
    }
    sq_t[l * Z_DIM + tid] = aq;
    skb_t[l * Z_DIM + tid] = ak;
  }
}

// ---------------------------------------------------------------------------
// Fused streaming kernel. 12288 blocks, odd = m-part, even = z-part.
//
// m-part: out_m[n][l][c] = msa[n][l][:] @ Wmsa[:,c] + add_m[l][c]
//   one column per thread, Wmsa column (23 f32) in VGPRs, 32 rows/block.
//   msa row elements are wave-uniform broadcast loads. unroll 2 to bound
//   register pressure.
//
// z-part: out_z[i][j][c] = sq[j][c] + skb[i][c] + Wpos[clip(j-i)+-32][c]
//   float4 everywhere; uniform-branch fast paths for blocks fully past the
//   clamp (constant Wpos row folded into the per-thread base).
// ---------------------------------------------------------------------------
__global__ __launch_bounds__(256) void fused_kernel(
    const float* __restrict__ msa, const float* __restrict__ Wmsa,
    const float* __restrict__ add_m, const float* __restrict__ sq_t,
    const float* __restrict__ skb_t, const float* __restrict__ Wpos,
    float* __restrict__ out_m, float* __restrict__ out_z) {
  const int bid = blockIdx.x >> 1;

  if (blockIdx.x & 1) {
    // ------------------------- m-part -------------------------
    const int tid = threadIdx.x;
    float w[MSA_D];
#pragma unroll
    for (int k = 0; k < MSA_D; ++k) w[k] = Wmsa[k * M_DIM + tid];

    const long r0 = (long)bid * M_ROWS_PER_BLOCK;  // flat row n*L + l
    const int  l0 = (int)(r0 % L_SEQ);             // 768 % 32 == 0: no wrap
    const float* __restrict__ mrow = msa + r0 * MSA_D;
    const float* __restrict__ arow = add_m + (long)l0 * M_DIM + tid;
    float* __restrict__ orow = out_m + r0 * M_DIM + tid;

#pragma unroll 2
    for (int r = 0; r < M_ROWS_PER_BLOCK; ++r) {
      float acc = arow[r * M_DIM];
#pragma unroll
      for (int k = 0; k < MSA_D; ++k)
        acc = fmaf(mrow[r * MSA_D + k], w[k], acc);
      orow[r * M_DIM] = acc;
    }
  } else {
    // ------------------------- z-part -------------------------
    const int i  = bid >> 3;
    const int j0 = (bid & 7) * 96;           // 96 j's per block
    const int c4 = threadIdx.x & 31;         // float4 column slot
    const int jl = threadIdx.x >> 5;         // 0..7

    const float4* __restrict__ sq4 = (const float4*)sq_t;
    const float4* __restrict__ wp4 = (const float4*)Wpos;

    float4 base = ((const float4*)skb_t)[i * (Z_DIM / 4) + c4];
    float4* __restrict__ out4 =
        (float4*)out_z + ((long)i * L_SEQ + j0) * (Z_DIM / 4);

    if (j0 - i >= RELCLIP) {
      // all rel clipped to +32 -> Wpos row 64, fold into base
      const float4 wv = wp4[(2 * RELCLIP) * (Z_DIM / 4) + c4];
      base.x += wv.x; base.y += wv.y; base.z += wv.z; base.w += wv.w;
#pragma unroll 2
      for (int t = 0; t < 12; ++t) {
        const int j = jl + 8 * t;
        const float4 q = sq4[(j0 + j) * (Z_DIM / 4) + c4];
        float4 o;
        o.x = base.x + q.x; o.y = base.y + q.y;
        o.z = base.z + q.z; o.w = base.w + q.w;
        out4[j * (Z_DIM / 4) + c4] = o;
      }
    } else if (j0 + 95 - i <= -RELCLIP) {
      // all rel clipped to -32 -> Wpos row 0, fold into base
      const float4 wv = wp4[c4];
      base.x += wv.x; base.y += wv.y; base.z += wv.z; base.w += wv.w;
#pragma unroll 2
      for (int t = 0; t < 12; ++t) {
        const int j = jl + 8 * t;
        const float4 q = sq4[(j0 + j) * (Z_DIM / 4) + c4];
        float4 o;
        o.x = base.x + q.x; o.y = base.y + q.y;
        o.z = base.z + q.z; o.w = base.w + q.w;
        out4[j * (Z_DIM / 4) + c4] = o;
      }
    } else {
      // diagonal band: per-j gather from Wpos
#pragma unroll 2
      for (int t = 0; t < 12; ++t) {
        const int j = jl + 8 * t;
        int rel = (j0 + j) - i;
        rel = rel < -RELCLIP ? -RELCLIP : (rel > RELCLIP ? RELCLIP : rel);
        const float4 q  = sq4[(j0 + j) * (Z_DIM / 4) + c4];
        const float4 wv = wp4[(rel + RELCLIP) * (Z_DIM / 4) + c4];
        float4 o;
        o.x = base.x + q.x + wv.x; o.y = base.y + q.y + wv.y;
        o.z = base.z + q.z + wv.z; o.w = base.w + q.w + wv.w;
        out4[j * (Z_DIM / 4) + c4] = o;
      }
    }
  }
}

extern "C" void kernel_launch(void* const* d_in, const int* in_sizes, int n_in,
                              void* d_out, int out_size, void* d_ws, size_t ws_size,
                              hipStream_t stream) {
  const float* seq   = (const float*)d_in[0];
  const float* msa   = (const float*)d_in[1];
  const float* Wmsa  = (const float*)d_in[2];
  const float* bmsa  = (const float*)d_in[3];
  const float* Ws    = (const float*)d_in[4];
  const float* bs    = (const float*)d_in[5];
  const float* Wq    = (const float*)d_in[6];
  const float* bq    = (const float*)d_in[7];
  const float* Wk    = (const float*)d_in[8];
  const float* bk    = (const float*)d_in[9];
  const float* Wpos  = (const float*)d_in[10];
  const float* bpos  = (const float*)d_in[11];
  const float* Wpos2 = (const float*)d_in[12];
  const float* bpos2 = (const float*)d_in[13];

  float* out_m = (float*)d_out;
  float* out_z = out_m + (long)N_MSA * L_SEQ * M_DIM;

  float* add_m = (float*)d_ws;                 // [768][256]
  float* sq_t  = add_m + L_SEQ * M_DIM;        // [768][128]
  float* skb_t = sq_t + L_SEQ * Z_DIM;         // [768][128]

  precompute_kernel<<<L_SEQ, 256, 0, stream>>>(seq, Ws, bs, bmsa, Wq, bq, Wk, bk,
                                               bpos, Wpos2, bpos2,
                                               add_m, sq_t, skb_t);
  fused_kernel<<<MBLOCKS + ZBLOCKS, 256, 0, stream>>>(msa, Wmsa, add_m, sq_t,
                                                      skb_t, Wpos, out_m, out_z);
}